// Round 4
// baseline (7010.200 us; speedup 1.0000x reference)
//
#include <hip/hip_runtime.h>
#include <hip/hip_bf16.h>
#include <stdint.h>

#define B_ 64
#define S_ 512
#define I_ 256
#define H_ 512

typedef __attribute__((ext_vector_type(8))) short bf16x8;
typedef __attribute__((ext_vector_type(4))) float f32x4;

__device__ __forceinline__ ushort f2bf(float f) {
  union { float f; uint32_t u; } c; c.f = f;
  uint32_t u = c.u + 0x7FFFu + ((c.u >> 16) & 1u);
  return (ushort)(u >> 16);
}
__device__ __forceinline__ float bf2f(ushort s) {
  union { uint32_t u; float f; } c; c.u = ((uint32_t)s) << 16; return c.f;
}

// ---------------- convert kernels ----------------
__global__ __launch_bounds__(256) void conv_inputs(const float* __restrict__ x,
                                                   ushort* __restrict__ y) {
  int i = blockIdx.x * 256 + threadIdx.x;  // 2,097,152 float4 groups
  float4 v = ((const float4*)x)[i];
  ushort4 o;
  o.x = f2bf(v.x); o.y = f2bf(v.y); o.z = f2bf(v.z); o.w = f2bf(v.w);
  ((ushort4*)y)[i] = o;
}

__global__ __launch_bounds__(256) void conv_w(const float* __restrict__ a,
                                              const float* __restrict__ b,
                                              const float* __restrict__ c,
                                              ushort* __restrict__ y) {
  int i = blockIdx.x * 256 + threadIdx.x;  // 98,304 groups of 4
  int e = i * 4;
  int g = e >> 17;           // 131072 elems per matrix
  int rem = e & 131071;
  const float* src = (g == 0) ? a : (g == 1) ? b : c;
  float4 v = *(const float4*)(src + rem);
  ushort4 o;
  o.x = f2bf(v.x); o.y = f2bf(v.y); o.z = f2bf(v.z); o.w = f2bf(v.w);
  *(ushort4*)(y + e) = o;
}

// ---------------- input-projection GEMM ----------------
// C[m,n] = sum_k A[m,k]*Bw[n,k] + bias;  m = b*512+s (32768), n = g*512+h (1536), K=256
// output layout gi[s][g][b][h] (bf16) for streaming consumption by the scan.
__global__ __launch_bounds__(256) void gemm_gi(const ushort* __restrict__ A,
                                               const ushort* __restrict__ Bw,
                                               const float* __restrict__ b_ir,
                                               const float* __restrict__ b_iz,
                                               const float* __restrict__ b_in,
                                               ushort* __restrict__ gi) {
  __shared__ ushort As[128][40];  // +8 pad: 16B-aligned rows, decorrelated banks
  __shared__ ushort Bs[128][40];
  const int m0 = blockIdx.x * 128;
  const int n0 = blockIdx.y * 128;
  const int tid = threadIdx.x;
  const int lane = tid & 63, wid = tid >> 6;
  const int wm = wid & 1, wn = wid >> 1;
  f32x4 acc[4][4];
  const f32x4 zz = {0.f, 0.f, 0.f, 0.f};
#pragma unroll
  for (int mi = 0; mi < 4; mi++)
#pragma unroll
    for (int ni = 0; ni < 4; ni++) acc[mi][ni] = zz;

  const int r = tid >> 2;
  const int ccol = (tid & 3) * 8;
  for (int kk = 0; kk < 256; kk += 32) {
    __syncthreads();
    *(uint4*)&As[r][ccol]      = *(const uint4*)&A[(size_t)(m0 + r) * 256 + kk + ccol];
    *(uint4*)&As[r + 64][ccol] = *(const uint4*)&A[(size_t)(m0 + r + 64) * 256 + kk + ccol];
    *(uint4*)&Bs[r][ccol]      = *(const uint4*)&Bw[(size_t)(n0 + r) * 256 + kk + ccol];
    *(uint4*)&Bs[r + 64][ccol] = *(const uint4*)&Bw[(size_t)(n0 + r + 64) * 256 + kk + ccol];
    __syncthreads();
    const int q8 = (lane >> 4) * 8;
    bf16x8 af[4], bf[4];
#pragma unroll
    for (int mi = 0; mi < 4; mi++)
      af[mi] = *(const bf16x8*)&As[wm * 64 + mi * 16 + (lane & 15)][q8];
#pragma unroll
    for (int ni = 0; ni < 4; ni++)
      bf[ni] = *(const bf16x8*)&Bs[wn * 64 + ni * 16 + (lane & 15)][q8];
#pragma unroll
    for (int mi = 0; mi < 4; mi++)
#pragma unroll
      for (int ni = 0; ni < 4; ni++)
        acc[mi][ni] = __builtin_amdgcn_mfma_f32_16x16x32_bf16(af[mi], bf[ni], acc[mi][ni], 0, 0, 0);
  }
#pragma unroll
  for (int ni = 0; ni < 4; ni++) {
    int n = n0 + wn * 64 + ni * 16 + (lane & 15);
    int g = n >> 9, hh = n & 511;
    const float* bp = (g == 0) ? b_ir : (g == 1) ? b_iz : b_in;
    float bias = bp[hh];
#pragma unroll
    for (int mi = 0; mi < 4; mi++) {
      int mb = m0 + wm * 64 + mi * 16 + ((lane >> 4) << 2);
#pragma unroll
      for (int v = 0; v < 4; v++) {
        int m = mb + v;
        int s = m & 511, b = m >> 9;
        size_t idx = (((size_t)s * 3 + g) * 64 + b) * 512 + hh;
        gi[idx] = f2bf(acc[mi][ni][v] + bias);
      }
    }
  }
}

// ---------------- persistent scan ----------------
#define CPG 16  // workgroups (column slices)
#define HS 32   // H columns per workgroup
#define NG 4    // time-interleaved batch groups per WG

// One flag WORD per WG per group; group's 16 words = one 64B line
// (line stride 128B between groups). Poll: one 4B/lane load + __all.
__device__ __forceinline__ void wave_poll16(const int* flags, int lane, int tgt) {
  const int* fp = flags + (lane & 15);
  for (;;) {
    int v = __hip_atomic_load(fp, __ATOMIC_RELAXED, __HIP_MEMORY_SCOPE_AGENT);
    if (__all(v >= tgt)) break;
    __builtin_amdgcn_s_sleep(1);
  }
}

// 16 WGs; WG cc owns columns [cc*32, cc*32+32) of ALL 4 batch groups.
// Per step, 4 phases (one per group) — each group's IF exchange latency
// (drain-ack, flag propagation, poll) is covered by the other 3 phases.
// Wave roles: 0-2 = MFMA (gate r/z/n); 7 = poller of next group; all 8 =
// elementwise. Per-group flag/ping-pong protocol identical to the
// verified R3 scheme, just interleaved.
__global__ __launch_bounds__(512, 2) void gru_scan(
    const float* __restrict__ h0p, const float* __restrict__ w_hr,
    const float* __restrict__ w_hz, const float* __restrict__ w_hn,
    const float* __restrict__ b_hr, const float* __restrict__ b_hz,
    const float* __restrict__ b_hn, const ushort* __restrict__ gi,
    ushort* __restrict__ hbuf, int* __restrict__ counters, float* __restrict__ out) {
  const int cc = blockIdx.x;  // 0..15 column slice
  const int hc0 = cc * HS;
  const int tid = threadIdx.x, lane = tid & 63, wid = tid >> 6;

  __shared__ float atile[3][16][HS + 1];

  const size_t BH = (size_t)B_ * H_;
  const int gm = tid >> 5, gn = tid & 31;

  // per-thread fixed-column recurrent biases — registers
  const float bhr = b_hr[hc0 + gn];
  const float bhz = b_hz[hc0 + gn];
  const float bhn = b_hn[hc0 + gn];

  // h state: one register per group (thread owns (g, gm, gn) forever)
  float hprev[NG];
#pragma unroll
  for (int g = 0; g < NG; g++) {
    hprev[g] = h0p[(g * 16 + gm) * H_ + hc0 + gn];
    // buf[1] read at t=0 — write-through agent store (visible without wbl2)
    __hip_atomic_store(&hbuf[BH + (g * 16 + gm) * H_ + hc0 + gn], f2bf(hprev[g]),
                       __ATOMIC_RELAXED, __HIP_MEMORY_SCOPE_AGENT);
  }

  // Recurrent-weight B-fragments, resident in VGPRs for the whole kernel.
  // Shared across all 4 batch groups (weights are batch-independent).
  bf16x8 bfrag[2][16];
  if (wid < 3) {
    const float* W = (wid == 0) ? w_hr : (wid == 1) ? w_hz : w_hn;
#pragma unroll
    for (int j = 0; j < 2; j++) {
      int row = hc0 + j * 16 + (lane & 15);
      const float* Wr = W + (size_t)row * H_ + ((lane >> 4) << 3);
#pragma unroll
      for (int ks = 0; ks < 16; ks++) {
        const float4 x = *(const float4*)(Wr + ks * 32);
        const float4 y = *(const float4*)(Wr + ks * 32 + 4);
        bf16x8 f;
        f[0] = (short)f2bf(x.x); f[1] = (short)f2bf(x.y);
        f[2] = (short)f2bf(x.z); f[3] = (short)f2bf(x.w);
        f[4] = (short)f2bf(y.x); f[5] = (short)f2bf(y.y);
        f[6] = (short)f2bf(y.z); f[7] = (short)f2bf(y.w);
        bfrag[j][ks] = f;
      }
    }
  }

  // gi for t=0, all groups — in flight while we publish/wait for h0
  ushort cr[NG], cz[NG], cn[NG];
#pragma unroll
  for (int g = 0; g < NG; g++) {
    size_t o = (size_t)(g * 16 + gm) * H_ + hc0 + gn;
    cr[g] = gi[o]; cz[g] = gi[o + BH]; cn[g] = gi[o + 2 * BH];
  }

  // release h0 for all groups: per-wave drain → barrier → 4 parallel flag stores
  asm volatile("s_waitcnt vmcnt(0)" ::: "memory");
  asm volatile("s_barrier" ::: "memory");
  if (tid < NG)
    __hip_atomic_store(&counters[tid * 32 + cc], 1, __ATOMIC_RELAXED, __HIP_MEMORY_SCOPE_AGENT);
  if (wid == 7) {
    wave_poll16(counters, lane, 1);  // group 0 ready for t=0
    __builtin_amdgcn_fence(__ATOMIC_ACQUIRE, "agent");  // waitcnt + inv (no wbl2)
  }
  asm volatile("s_barrier" ::: "memory");

  for (int t = 0; t < S_; t++) {
#pragma unroll
    for (int g = 0; g < NG; g++) {
      const ushort* hsrc = hbuf + ((t + 1) & 1) * BH + (size_t)(g * 16) * H_;
      if (wid < 3) {
        const ushort* hb = hsrc + (lane & 15) * H_ + ((lane >> 4) << 3);
        f32x4 acc0 = {0.f, 0.f, 0.f, 0.f}, acc1 = {0.f, 0.f, 0.f, 0.f};
#pragma unroll
        for (int half = 0; half < 2; half++) {
          bf16x8 a[8];
#pragma unroll
          for (int ks = 0; ks < 8; ks++) a[ks] = *(const bf16x8*)(hb + half * 256 + ks * 32);
#pragma unroll
          for (int ks = 0; ks < 8; ks++) {
            acc0 = __builtin_amdgcn_mfma_f32_16x16x32_bf16(a[ks], bfrag[0][half * 8 + ks], acc0, 0, 0, 0);
            acc1 = __builtin_amdgcn_mfma_f32_16x16x32_bf16(a[ks], bfrag[1][half * 8 + ks], acc1, 0, 0, 0);
          }
        }
        const int rr = (lane >> 4) << 2, nn0 = lane & 15;
#pragma unroll
        for (int v = 0; v < 4; v++) {
          atile[wid][rr + v][nn0] = acc0[v];
          atile[wid][rr + v][16 + nn0] = acc1[v];
        }
      }
      // wave 7: poll NEXT group (released 3 phases ago → usually already set),
      // then acquire-fence so next phase's h loads see fresh lines.
      if (wid == 7 && !(t == S_ - 1 && g == NG - 1)) {
        int g2 = (g + 1) & (NG - 1);
        int tgt = (g < NG - 1) ? (t + 1) : (t + 2);
        wave_poll16(counters + g2 * 32, lane, tgt);
        __builtin_amdgcn_fence(__ATOMIC_ACQUIRE, "agent");
      }
      // atile hand-off (LDS) + poll-fence ordering: lgkm drain + raw barrier;
      // global ops (out stores, gi prefetch) stay in flight.
      asm volatile("s_waitcnt lgkmcnt(0)\ns_barrier" ::: "memory");

      float hnew;
      {
        float ar = atile[0][gm][gn], az = atile[1][gm][gn], an = atile[2][gm][gn];
        float r = 1.f / (1.f + __expf(-(bf2f(cr[g]) + ar + bhr)));
        float z = 1.f / (1.f + __expf(-(bf2f(cz[g]) + az + bhz)));
        float narg = bf2f(cn[g]) + r * (an + bhn);
        float nv = 2.f / (1.f + __expf(-2.f * narg)) - 1.f;
        hnew = (1.f - z) * nv + z * hprev[g];
        hprev[g] = hnew;
        // write-through agent store: IF-visible once vmcnt drains (no wbl2)
        __hip_atomic_store(&hbuf[(t & 1) * BH + (g * 16 + gm) * H_ + hc0 + gn], f2bf(hnew),
                           __ATOMIC_RELAXED, __HIP_MEMORY_SCOPE_AGENT);
      }
      // release: per-wave drain → barrier (all drained) → parallel flag store
      asm volatile("s_waitcnt vmcnt(0)" ::: "memory");
      asm volatile("s_barrier" ::: "memory");
      if (tid == 0 && t + 1 < S_)
        __hip_atomic_store(&counters[g * 32 + cc], t + 2, __ATOMIC_RELAXED, __HIP_MEMORY_SCOPE_AGENT);

      // out stores AFTER the drain point: 3 phases of slack before the next
      // drain that touches them; never in the release path.
      out[((size_t)(g * 16 + gm) * S_ + t) * H_ + hc0 + gn] = hnew;
      if (t == S_ - 1) out[(size_t)B_ * S_ * H_ + (g * 16 + gm) * H_ + hc0 + gn] = hnew;

      // gi prefetch for (g, t+1) — a full 4-phase round of cover
      {
        int tn = (t + 1 < S_) ? t + 1 : t;
        size_t nb = (size_t)tn * 3 * BH + (size_t)(g * 16 + gm) * H_ + hc0 + gn;
        cr[g] = gi[nb]; cz[g] = gi[nb + BH]; cn[g] = gi[nb + 2 * BH];
      }
    }
  }
}

// ---------------- launcher ----------------
extern "C" void kernel_launch(void* const* d_in, const int* in_sizes, int n_in,
                              void* d_out, int out_size, void* d_ws, size_t ws_size,
                              hipStream_t stream) {
  const float* inputs = (const float*)d_in[0];
  const float* hid    = (const float*)d_in[1];
  const float* w_ir   = (const float*)d_in[2];
  const float* w_iz   = (const float*)d_in[3];
  const float* w_in   = (const float*)d_in[4];
  const float* b_ir   = (const float*)d_in[5];
  const float* b_iz   = (const float*)d_in[6];
  const float* b_in   = (const float*)d_in[7];
  const float* w_hr   = (const float*)d_in[8];
  const float* w_hz   = (const float*)d_in[9];
  const float* w_hn   = (const float*)d_in[10];
  const float* b_hr   = (const float*)d_in[11];
  const float* b_hz   = (const float*)d_in[12];
  const float* b_hn   = (const float*)d_in[13];
  float* out = (float*)d_out;

  char* ws = (char*)d_ws;
  ushort* wsA  = (ushort*)(ws);                // inputs bf16: 16,777,216 B
  ushort* wsW  = (ushort*)(ws + 16777216);     // W_i bf16:      786,432 B
  ushort* wsGi = (ushort*)(ws + 17563648);     // gi bf16:   100,663,296 B
  ushort* wsH  = (ushort*)(ws + 118226944);    // h ping-pong:   131,072 B
  int*    wsC  = (int*)(ws + 118358016);       // flag lines:      512 B

  hipMemsetAsync(wsC, 0, 4 * 32 * 4, stream);
  conv_inputs<<<8192, 256, 0, stream>>>(inputs, wsA);
  conv_w<<<384, 256, 0, stream>>>(w_ir, w_iz, w_in, wsW);
  gemm_gi<<<dim3(256, 12), 256, 0, stream>>>(wsA, wsW, b_ir, b_iz, b_in, wsGi);
  gru_scan<<<CPG, 512, 0, stream>>>(hid, w_hr, w_hz, w_hn, b_hr, b_hz, b_hn,
                                    wsGi, wsH, wsC, out);
}

// Round 7
// 1713.615 us; speedup vs baseline: 4.0909x; 4.0909x over previous
//
#include <hip/hip_runtime.h>
#include <hip/hip_bf16.h>
#include <stdint.h>

#define B_ 64
#define S_ 512
#define I_ 256
#define H_ 512

typedef __attribute__((ext_vector_type(8))) short bf16x8;
typedef __attribute__((ext_vector_type(4))) float f32x4;

__device__ __forceinline__ ushort f2bf(float f) {
  union { float f; uint32_t u; } c; c.f = f;
  uint32_t u = c.u + 0x7FFFu + ((c.u >> 16) & 1u);
  return (ushort)(u >> 16);
}
__device__ __forceinline__ float bf2f(ushort s) {
  union { uint32_t u; float f; } c; c.u = ((uint32_t)s) << 16; return c.f;
}

// ---------------- convert kernels ----------------
__global__ __launch_bounds__(256) void conv_inputs(const float* __restrict__ x,
                                                   ushort* __restrict__ y) {
  int i = blockIdx.x * 256 + threadIdx.x;  // 2,097,152 float4 groups
  float4 v = ((const float4*)x)[i];
  ushort4 o;
  o.x = f2bf(v.x); o.y = f2bf(v.y); o.z = f2bf(v.z); o.w = f2bf(v.w);
  ((ushort4*)y)[i] = o;
}

__global__ __launch_bounds__(256) void conv_w(const float* __restrict__ a,
                                              const float* __restrict__ b,
                                              const float* __restrict__ c,
                                              ushort* __restrict__ y) {
  int i = blockIdx.x * 256 + threadIdx.x;  // 98,304 groups of 4
  int e = i * 4;
  int g = e >> 17;           // 131072 elems per matrix
  int rem = e & 131071;
  const float* src = (g == 0) ? a : (g == 1) ? b : c;
  float4 v = *(const float4*)(src + rem);
  ushort4 o;
  o.x = f2bf(v.x); o.y = f2bf(v.y); o.z = f2bf(v.z); o.w = f2bf(v.w);
  *(ushort4*)(y + e) = o;
}

// ---------------- input-projection GEMM ----------------
__global__ __launch_bounds__(256) void gemm_gi(const ushort* __restrict__ A,
                                               const ushort* __restrict__ Bw,
                                               const float* __restrict__ b_ir,
                                               const float* __restrict__ b_iz,
                                               const float* __restrict__ b_in,
                                               ushort* __restrict__ gi) {
  __shared__ ushort As[128][40];
  __shared__ ushort Bs[128][40];
  const int m0 = blockIdx.x * 128;
  const int n0 = blockIdx.y * 128;
  const int tid = threadIdx.x;
  const int lane = tid & 63, wid = tid >> 6;
  const int wm = wid & 1, wn = wid >> 1;
  f32x4 acc[4][4];
  const f32x4 zz = {0.f, 0.f, 0.f, 0.f};
#pragma unroll
  for (int mi = 0; mi < 4; mi++)
#pragma unroll
    for (int ni = 0; ni < 4; ni++) acc[mi][ni] = zz;

  const int r = tid >> 2;
  const int ccol = (tid & 3) * 8;
  for (int kk = 0; kk < 256; kk += 32) {
    __syncthreads();
    *(uint4*)&As[r][ccol]      = *(const uint4*)&A[(size_t)(m0 + r) * 256 + kk + ccol];
    *(uint4*)&As[r + 64][ccol] = *(const uint4*)&A[(size_t)(m0 + r + 64) * 256 + kk + ccol];
    *(uint4*)&Bs[r][ccol]      = *(const uint4*)&Bw[(size_t)(n0 + r) * 256 + kk + ccol];
    *(uint4*)&Bs[r + 64][ccol] = *(const uint4*)&Bw[(size_t)(n0 + r + 64) * 256 + kk + ccol];
    __syncthreads();
    const int q8 = (lane >> 4) * 8;
    bf16x8 af[4], bf[4];
#pragma unroll
    for (int mi = 0; mi < 4; mi++)
      af[mi] = *(const bf16x8*)&As[wm * 64 + mi * 16 + (lane & 15)][q8];
#pragma unroll
    for (int ni = 0; ni < 4; ni++)
      bf[ni] = *(const bf16x8*)&Bs[wn * 64 + ni * 16 + (lane & 15)][q8];
#pragma unroll
    for (int mi = 0; mi < 4; mi++)
#pragma unroll
      for (int ni = 0; ni < 4; ni++)
        acc[mi][ni] = __builtin_amdgcn_mfma_f32_16x16x32_bf16(af[mi], bf[ni], acc[mi][ni], 0, 0, 0);
  }
#pragma unroll
  for (int ni = 0; ni < 4; ni++) {
    int n = n0 + wn * 64 + ni * 16 + (lane & 15);
    int g = n >> 9, hh = n & 511;
    const float* bp = (g == 0) ? b_ir : (g == 1) ? b_iz : b_in;
    float bias = bp[hh];
#pragma unroll
    for (int mi = 0; mi < 4; mi++) {
      int mb = m0 + wm * 64 + mi * 16 + ((lane >> 4) << 2);
#pragma unroll
      for (int v = 0; v < 4; v++) {
        int m = mb + v;
        int s = m & 511, b = m >> 9;
        size_t idx = (((size_t)s * 3 + g) * 64 + b) * 512 + hh;
        gi[idx] = f2bf(acc[mi][ni][v] + bias);
      }
    }
  }
}

// ---------------- persistent scan ----------------
#define CPG 16   // workgroups per batch-group
#define HS 32    // H columns per workgroup
#define NWG 256  // launched WGs (surplus exits after claiming)

// HW_REG_XCC_ID (id=20), offset 0, width 32: imm = ((32-1)<<11) | (0<<6) | 20
#define XCC_GETREG_IMM ((31 << 11) | 20)

// Mode-scoped h/flag stores. Fast (group is XCD-local): workgroup scope =
// plain store, committed to the local XCD's L2 at vmcnt ack (cheap).
// Slow: agent scope (write-through toward IF) — exactly the verified R3.
__device__ __forceinline__ void st_u16(ushort* p, ushort v, bool fast) {
  if (fast) __hip_atomic_store(p, v, __ATOMIC_RELAXED, __HIP_MEMORY_SCOPE_WORKGROUP);
  else      __hip_atomic_store(p, v, __ATOMIC_RELAXED, __HIP_MEMORY_SCOPE_AGENT);
}
__device__ __forceinline__ void st_flag(int* p, int v, bool fast) {
  if (fast) __hip_atomic_store(p, v, __ATOMIC_RELAXED, __HIP_MEMORY_SCOPE_WORKGROUP);
  else      __hip_atomic_store(p, v, __ATOMIC_RELAXED, __HIP_MEMORY_SCOPE_AGENT);
}

// Poll the group's 16-flag line (one 4B/lane agent load + __all), then a
// single agent acquire fence — identical in both modes (R3-verified path).
// In fast mode the flag line is dirty in the local L2, so both the poll hit
// and the h reload stay XCD-local (dirty lines survive the acquire inv).
__device__ __forceinline__ void poll16(const int* flags, int lane, int tgt) {
  const int* fp = flags + (lane & 15);
  for (;;) {
    int v = __hip_atomic_load(fp, __ATOMIC_RELAXED, __HIP_MEMORY_SCOPE_AGENT);
    if (__all(v >= tgt)) break;
    __builtin_amdgcn_s_sleep(1);
  }
  __builtin_amdgcn_fence(__ATOMIC_ACQUIRE, "agent");
}

// counters layout (ints): [0..127] flags (4 groups x 32-int stride)
// [128..135] claimA census per XCD   [144..151] claimB fast slots per XCD
// [160] claimC slow slots  [168] checkin  [172] decider  [176] decision
__global__ __launch_bounds__(512, 2) void gru_scan(
    const float* __restrict__ h0p, const float* __restrict__ w_hr,
    const float* __restrict__ w_hz, const float* __restrict__ w_hn,
    const float* __restrict__ b_hr, const float* __restrict__ b_hz,
    const float* __restrict__ b_hn, const ushort* __restrict__ gi,
    ushort* __restrict__ hbuf, int* __restrict__ counters, float* __restrict__ out) {
  const int tid = threadIdx.x, lane = tid & 63, wid = tid >> 6;

  __shared__ float atile[3][16][HS + 1];
  __shared__ int s_group, s_cc, s_fast;

  // ---- claim phase: hang-proof by construction.
  // Every WG checks in BEFORE any waiting. A single leader (ticket 0) does a
  // BOUNDED wait for the full census, then always publishes a decision;
  // followers wait only on the decision. Any anomaly -> slow mode (= R3). ----
  if (tid == 0) {
#if __has_builtin(__builtin_amdgcn_s_getreg)
    unsigned xcc = __builtin_amdgcn_s_getreg(XCC_GETREG_IMM) & 7u;
    const int have_xcc = 1;
#else
    unsigned xcc = 0;
    const int have_xcc = 0;
#endif
    int* claimA   = counters + 128;
    int* claimB   = counters + 144;
    int* claimC   = counters + 160;
    int* checkin  = counters + 168;
    int* decider  = counters + 172;
    int* decision = counters + 176;
    __hip_atomic_fetch_add(&claimA[xcc], 1, __ATOMIC_RELAXED, __HIP_MEMORY_SCOPE_AGENT);
    __hip_atomic_fetch_add(checkin, 1, __ATOMIC_RELEASE, __HIP_MEMORY_SCOPE_AGENT);
    int ticket = __hip_atomic_fetch_add(decider, 1, __ATOMIC_RELAXED, __HIP_MEMORY_SCOPE_AGENT);
    if (ticket == 0) {
      int ok = 0;
      for (int it = 0; it < (1 << 16); ++it) {  // bounded (~10 ms worst case)
        if (__hip_atomic_load(checkin, __ATOMIC_ACQUIRE, __HIP_MEMORY_SCOPE_AGENT) >= NWG) { ok = 1; break; }
        __builtin_amdgcn_s_sleep(2);
      }
      int fast = ok && have_xcc;
      if (fast)
        for (int x = 0; x < 4; x++)
          if (__hip_atomic_load(&claimA[x], __ATOMIC_RELAXED, __HIP_MEMORY_SCOPE_AGENT) < CPG)
            fast = 0;
      __hip_atomic_store(decision, fast ? 2 : 1, __ATOMIC_RELEASE, __HIP_MEMORY_SCOPE_AGENT);
    }
    int dec;
    do {
      dec = __hip_atomic_load(decision, __ATOMIC_ACQUIRE, __HIP_MEMORY_SCOPE_AGENT);
      if (!dec) __builtin_amdgcn_s_sleep(2);
    } while (!dec);  // leader always publishes -> bounded
    int fast = (dec == 2);
    int group = -1, cc = 0;
    if (fast) {
      if (xcc < 4) {
        int s = __hip_atomic_fetch_add(&claimB[xcc], 1, __ATOMIC_RELAXED, __HIP_MEMORY_SCOPE_AGENT);
        if (s < CPG) { group = (int)xcc; cc = s; }
      }
    } else {
      int s = __hip_atomic_fetch_add(claimC, 1, __ATOMIC_RELAXED, __HIP_MEMORY_SCOPE_AGENT);
      if (s < 4 * CPG) { group = s >> 4; cc = s & 15; }
    }
    s_group = group; s_cc = cc; s_fast = fast;
  }
  __syncthreads();
  const int group = s_group, cc = s_cc;
  const bool fast = (bool)s_fast;
  if (group < 0) return;  // surplus WG

  const int b0 = group * 16;
  const int hc0 = cc * HS;
  int* flags = counters + group * 32;  // one 64B flag line per group

  const size_t BH = (size_t)B_ * H_;
  const int gm = tid >> 5, gn = tid & 31;

  // per-thread fixed-column recurrent biases — registers
  const float bhr = b_hr[hc0 + gn];
  const float bhz = b_hz[hc0 + gn];
  const float bhn = b_hn[hc0 + gn];

  // h0 (register state; same thread owns (gm,gn) forever)
  float hprev = h0p[(b0 + gm) * H_ + hc0 + gn];
  st_u16(&hbuf[BH + (b0 + gm) * H_ + hc0 + gn], f2bf(hprev), fast);

  // Recurrent-weight B-fragments, resident in VGPRs for the whole kernel.
  bf16x8 bfrag[2][16];
  if (wid < 3) {
    const float* W = (wid == 0) ? w_hr : (wid == 1) ? w_hz : w_hn;
#pragma unroll
    for (int j = 0; j < 2; j++) {
      int row = hc0 + j * 16 + (lane & 15);
      const float* Wr = W + (size_t)row * H_ + ((lane >> 4) << 3);
#pragma unroll
      for (int ks = 0; ks < 16; ks++) {
        const float4 x = *(const float4*)(Wr + ks * 32);
        const float4 y = *(const float4*)(Wr + ks * 32 + 4);
        bf16x8 f;
        f[0] = (short)f2bf(x.x); f[1] = (short)f2bf(x.y);
        f[2] = (short)f2bf(x.z); f[3] = (short)f2bf(x.w);
        f[4] = (short)f2bf(y.x); f[5] = (short)f2bf(y.y);
        f[6] = (short)f2bf(y.z); f[7] = (short)f2bf(y.w);
        bfrag[j][ks] = f;
      }
    }
  }

  const size_t goff = (size_t)(b0 + gm) * H_ + hc0 + gn;

  // gi for t=0 — in flight while we publish/wait for h0
  ushort cr = gi[goff];
  ushort cz = gi[goff + BH];
  ushort cn = gi[goff + 2 * BH];

  // release h0: drain → barrier → one flag store per WG
  asm volatile("s_waitcnt vmcnt(0)" ::: "memory");
  asm volatile("s_barrier" ::: "memory");
  if (tid == 0) st_flag(&flags[cc], 1, fast);
  if (wid == 3) poll16(flags, lane, 1);
  asm volatile("s_barrier" ::: "memory");

  for (int t = 0; t < S_; t++) {
    const ushort* hsrc = hbuf + ((t + 1) & 1) * BH + b0 * H_;
    if (wid < 3) {
      const ushort* hb = hsrc + (lane & 15) * H_ + ((lane >> 4) << 3);
      f32x4 acc0 = {0.f, 0.f, 0.f, 0.f}, acc1 = {0.f, 0.f, 0.f, 0.f};
#pragma unroll
      for (int half = 0; half < 2; half++) {
        bf16x8 a[8];
#pragma unroll
        for (int ks = 0; ks < 8; ks++) a[ks] = *(const bf16x8*)(hb + half * 256 + ks * 32);
#pragma unroll
        for (int ks = 0; ks < 8; ks++) {
          acc0 = __builtin_amdgcn_mfma_f32_16x16x32_bf16(a[ks], bfrag[0][half * 8 + ks], acc0, 0, 0, 0);
          acc1 = __builtin_amdgcn_mfma_f32_16x16x32_bf16(a[ks], bfrag[1][half * 8 + ks], acc1, 0, 0, 0);
        }
      }
      const int rr = (lane >> 4) << 2, nn0 = lane & 15;
#pragma unroll
      for (int v = 0; v < 4; v++) {
        atile[wid][rr + v][nn0] = acc0[v];
        atile[wid][rr + v][16 + nn0] = acc1[v];
      }
    }
    // atile hand-off is LDS-only: drain lgkm + raw barrier; global ops
    // (out stores, gi prefetch) stay in flight.
    asm volatile("s_waitcnt lgkmcnt(0)\ns_barrier" ::: "memory");

    float hnew;
    {
      float ar = atile[0][gm][gn], az = atile[1][gm][gn], an = atile[2][gm][gn];
      float r = 1.f / (1.f + __expf(-(bf2f(cr) + ar + bhr)));
      float z = 1.f / (1.f + __expf(-(bf2f(cz) + az + bhz)));
      float narg = bf2f(cn) + r * (an + bhn);
      float nv = 2.f / (1.f + __expf(-2.f * narg)) - 1.f;
      hnew = (1.f - z) * nv + z * hprev;
      hprev = hnew;
      st_u16(&hbuf[(t & 1) * BH + (b0 + gm) * H_ + hc0 + gn], f2bf(hnew), fast);
    }
    // release: per-wave drain → barrier (all drained) → parallel flag store
    asm volatile("s_waitcnt vmcnt(0)" ::: "memory");
    asm volatile("s_barrier" ::: "memory");
    if (tid == 0 && t + 1 < S_) st_flag(&flags[cc], t + 2, fast);

    // out stores AFTER the drain point: a full poll window of slack.
    out[((size_t)(b0 + gm) * S_ + t) * H_ + hc0 + gn] = hnew;
    if (t == S_ - 1) out[(size_t)B_ * S_ * H_ + (b0 + gm) * H_ + hc0 + gn] = hnew;

    // gi prefetch for t+1 — latency hides under the poll
    {
      int tn = (t + 1 < S_) ? t + 1 : t;
      size_t nb = (size_t)tn * 3 * BH + goff;
      cr = gi[nb];
      cz = gi[nb + BH];
      cn = gi[nb + 2 * BH];
    }

    // Only wave 3 polls + acquires; MFMA waves keep prefetch in flight.
    if (wid == 3 && t + 1 < S_) poll16(flags, lane, t + 2);
    asm volatile("s_barrier" ::: "memory");
  }
}

// ---------------- launcher ----------------
extern "C" void kernel_launch(void* const* d_in, const int* in_sizes, int n_in,
                              void* d_out, int out_size, void* d_ws, size_t ws_size,
                              hipStream_t stream) {
  const float* inputs = (const float*)d_in[0];
  const float* hid    = (const float*)d_in[1];
  const float* w_ir   = (const float*)d_in[2];
  const float* w_iz   = (const float*)d_in[3];
  const float* w_in   = (const float*)d_in[4];
  const float* b_ir   = (const float*)d_in[5];
  const float* b_iz   = (const float*)d_in[6];
  const float* b_in   = (const float*)d_in[7];
  const float* w_hr   = (const float*)d_in[8];
  const float* w_hz   = (const float*)d_in[9];
  const float* w_hn   = (const float*)d_in[10];
  const float* b_hr   = (const float*)d_in[11];
  const float* b_hz   = (const float*)d_in[12];
  const float* b_hn   = (const float*)d_in[13];
  float* out = (float*)d_out;

  char* ws = (char*)d_ws;
  ushort* wsA  = (ushort*)(ws);                // inputs bf16: 16,777,216 B
  ushort* wsW  = (ushort*)(ws + 16777216);     // W_i bf16:      786,432 B
  ushort* wsGi = (ushort*)(ws + 17563648);     // gi bf16:   100,663,296 B
  ushort* wsH  = (ushort*)(ws + 118226944);    // h ping-pong:   131,072 B
  int*    wsC  = (int*)(ws + 118358016);       // flags+claim:     1,024 B

  hipMemsetAsync(wsC, 0, 1024, stream);
  conv_inputs<<<8192, 256, 0, stream>>>(inputs, wsA);
  conv_w<<<384, 256, 0, stream>>>(w_ir, w_iz, w_in, wsW);
  gemm_gi<<<dim3(256, 12), 256, 0, stream>>>(wsA, wsW, b_ir, b_iz, b_in, wsGi);
  gru_scan<<<NWG, 512, 0, stream>>>(hid, w_hr, w_hz, w_hn, b_hr, b_hz, b_hn,
                                    wsGi, wsH, wsC, out);
}